// Round 10
// baseline (189.772 us; speedup 1.0000x reference)
//
#include <hip/hip_runtime.h>
#include <hip/hip_bf16.h>

#define N_NODES 10000
#define N_EDGES 640000
#define IN_DIM  128
#define HID_DIM 256
#define OUT_DIM 128

#define MAXDEG     128     // deg ~ Binom(640k,1e-4): mean 64, P(>128) ~ 1e-11
#define NCHUNK     64
#define CEDGES     (N_EDGES / NCHUNK)        // 10000 edges per chunk
#define NPART      8
#define PART_NODES (N_NODES / NPART)         // 1250
#define HSTRIDE    10240                     // padded node stride in HO
#define SAGG_STR   136                       // LDS agg-tile row stride (ushorts), bank-pad

typedef __attribute__((ext_vector_type(8))) short short8;
typedef __attribute__((ext_vector_type(4))) float float4v;
typedef unsigned short ushort_t;
typedef unsigned int uint_t;

__device__ inline ushort_t f2bf(float f) {
    uint_t u = __float_as_uint(f);
    u += 0x7fffu + ((u >> 16) & 1u);
    return (ushort_t)(u >> 16);
}
__device__ inline float bf_lo(uint_t u) { return __uint_as_float(u << 16); }
__device__ inline float bf_hi(uint_t u) { return __uint_as_float(u & 0xffff0000u); }

// ---------------------------------------------------------------------------
// Prep: x -> bf16; weights -> transposed bf16.
// ---------------------------------------------------------------------------
#define PREP_X   (N_NODES * IN_DIM)
#define PREP_W1  (HID_DIM * (2 * IN_DIM))
#define PREP_W2  (OUT_DIM * HID_DIM)
#define PREP_TOTAL (PREP_X + PREP_W1 + 2 * PREP_W2)

__global__ void prep_kernel(const float* __restrict__ x,
                            const float* __restrict__ W1_l, const float* __restrict__ W1_r,
                            const float* __restrict__ W2_l, const float* __restrict__ W2_r,
                            ushort_t* __restrict__ xb,  ushort_t* __restrict__ w1t,
                            ushort_t* __restrict__ w2tl, ushort_t* __restrict__ w2tr) {
    int i = blockIdx.x * blockDim.x + threadIdx.x;
    if (i < PREP_X) {
        xb[i] = f2bf(x[i]);
    } else if (i < PREP_X + PREP_W1) {
        int j = i - PREP_X;
        int n = j >> 8, k = j & 255;            // w1t[n][k], n in [0,256)
        float v = (k < 128) ? W1_l[k * HID_DIM + n] : W1_r[(k - 128) * HID_DIM + n];
        w1t[j] = f2bf(v);
    } else if (i < PREP_X + PREP_W1 + PREP_W2) {
        int j = i - (PREP_X + PREP_W1);
        int n = j >> 8, k = j & 255;
        w2tl[j] = f2bf(W2_l[k * OUT_DIM + n]);
    } else if (i < PREP_TOTAL) {
        int j = i - (PREP_X + PREP_W1 + PREP_W2);
        int n = j >> 8, k = j & 255;
        w2tr[j] = f2bf(W2_r[k * OUT_DIM + n]);
    }
}

// ---------------------------------------------------------------------------
// CSR phase A: windowed histogram. Block (chunk, part) counts its chunk's
// edges that land in its 1250-node window (5 KB LDS, 8x less fixed cost
// than a 10k-counter hist) and flushes to its exclusive HO slice.
// ---------------------------------------------------------------------------
__global__ void hist_kernel(const int* __restrict__ dst, int* __restrict__ HO) {
    __shared__ int h[PART_NODES];
    const int part  = blockIdx.x & (NPART - 1);
    const int chunk = blockIdx.x >> 3;
    const int lo    = part * PART_NODES;
    const int tid   = threadIdx.x;
    for (int i = tid; i < PART_NODES; i += 256) h[i] = 0;
    __syncthreads();
    const int4* d4 = (const int4*)(dst + chunk * CEDGES);
    for (int i = tid; i < CEDGES / 4; i += 256) {
        int4 v = d4[i];
        int a;
        a = v.x - lo; if ((unsigned)a < (unsigned)PART_NODES) atomicAdd(&h[a], 1);
        a = v.y - lo; if ((unsigned)a < (unsigned)PART_NODES) atomicAdd(&h[a], 1);
        a = v.z - lo; if ((unsigned)a < (unsigned)PART_NODES) atomicAdd(&h[a], 1);
        a = v.w - lo; if ((unsigned)a < (unsigned)PART_NODES) atomicAdd(&h[a], 1);
    }
    __syncthreads();
    int* row = HO + chunk * HSTRIDE + lo;
    for (int i = tid; i < PART_NODES; i += 256) row[i] = h[i];
}

// ---------------------------------------------------------------------------
// CSR phase B: thread n converts column n of HO to exclusive per-chunk
// offsets (coalesced across n) and emits deg[n].
// ---------------------------------------------------------------------------
__global__ void scan_kernel(int* __restrict__ HO, int* __restrict__ deg) {
    int n = blockIdx.x * blockDim.x + threadIdx.x;
    if (n >= N_NODES) return;
    int s = 0;
    for (int b = 0; b < NCHUNK; ++b) {
        int v = HO[b * HSTRIDE + n];
        HO[b * HSTRIDE + n] = s;
        s += v;
    }
    deg[n] = s;
}

// ---------------------------------------------------------------------------
// CSR phase C: scatter with LDS cursors (slots pre-reserved by the scan —
// no global atomics). Block (chunk, part); plain byte-disjoint 2B stores.
// ---------------------------------------------------------------------------
__global__ void scatter_kernel(const int* __restrict__ src, const int* __restrict__ dst,
                               const int* __restrict__ HO, ushort_t* __restrict__ esrc2) {
    __shared__ int cur[PART_NODES];
    const int part  = blockIdx.x & (NPART - 1);
    const int chunk = blockIdx.x >> 3;
    const int lo    = part * PART_NODES;
    const int tid   = threadIdx.x;
    for (int i = tid; i < PART_NODES; i += 256)
        cur[i] = HO[chunk * HSTRIDE + lo + i];
    __syncthreads();
    const int base = chunk * CEDGES;
    for (int e = base + tid; e < base + CEDGES; e += 256) {
        int d = dst[e] - lo;
        if ((unsigned)d < (unsigned)PART_NODES) {
            int pos = atomicAdd(&cur[d], 1);          // LDS atomic, low contention
            if (pos < MAXDEG) esrc2[(lo + d) * MAXDEG + pos] = (ushort_t)src[e];
        }
    }
}

// ---------------------------------------------------------------------------
// Fused gather-mean + MFMA layer 1. Block = 16 nodes, 256 threads (4 waves).
// Phase 1: wave w gathers nodes w*4..w*4+3 (16 lanes x uint4 per row,
//   stride-16; shuffle-reduce over 4 slot-groups) into padded LDS tile.
// Phase 2: wave w computes output cols [w*64, w*64+64) of
//   h = relu([agg|x] @ [W1_l;W1_r] + b1), agg A-frags from LDS, x from global.
// ---------------------------------------------------------------------------
__global__ void gather_mfma1_kernel(const ushort_t* __restrict__ xb,
                                    const int* __restrict__ degp,
                                    const ushort_t* __restrict__ esrc2,
                                    const ushort_t* __restrict__ w1t,
                                    const float* __restrict__ b1,
                                    ushort_t* __restrict__ hb) {
    __shared__ ushort_t sagg[16 * SAGG_STR];
    const int wrow = blockIdx.x * 16;
    const int tid  = threadIdx.x;
    const int w = tid >> 6;            // wave 0..3
    const int l = tid & 63;
    const int g = l >> 4;              // neighbor slot group 0..3
    const int c = l & 15;              // 16B column 0..15

    const uint4* f = (const uint4*)xb;     // 16 uint4 per 128-dim row
    for (int i = 0; i < 4; ++i) {
        const int r = w * 4 + i;
        const int n = wrow + r;
        const int deg = min(degp[n], MAXDEG);
        const ushort_t* idx = esrc2 + n * MAXDEG;
        float a0=0,a1=0,a2=0,a3=0,a4=0,a5=0,a6=0,a7=0;
        for (int e = g; e < deg; e += 4) {
            uint4 u = f[(int)idx[e] * 16 + c];
            a0 += bf_lo(u.x); a1 += bf_hi(u.x);
            a2 += bf_lo(u.y); a3 += bf_hi(u.y);
            a4 += bf_lo(u.z); a5 += bf_hi(u.z);
            a6 += bf_lo(u.w); a7 += bf_hi(u.w);
        }
#pragma unroll
        for (int off = 32; off >= 16; off >>= 1) {
            a0 += __shfl_down(a0, off); a1 += __shfl_down(a1, off);
            a2 += __shfl_down(a2, off); a3 += __shfl_down(a3, off);
            a4 += __shfl_down(a4, off); a5 += __shfl_down(a5, off);
            a6 += __shfl_down(a6, off); a7 += __shfl_down(a7, off);
        }
        if (g == 0) {
            const float dinv = (deg > 0) ? 1.0f / (float)deg : 0.0f;
            uint4 o;
            o.x = (uint_t)f2bf(a0 * dinv) | ((uint_t)f2bf(a1 * dinv) << 16);
            o.y = (uint_t)f2bf(a2 * dinv) | ((uint_t)f2bf(a3 * dinv) << 16);
            o.z = (uint_t)f2bf(a4 * dinv) | ((uint_t)f2bf(a5 * dinv) << 16);
            o.w = (uint_t)f2bf(a6 * dinv) | ((uint_t)f2bf(a7 * dinv) << 16);
            *(uint4*)(&sagg[r * SAGG_STR + c * 8]) = o;
        }
    }
    __syncthreads();

    // Phase 2: MFMA. m=lane&15, q=lane>>4. A[m][k=q*8+j (+32s)], B=Wt rows.
    const int m = l & 15, q = l >> 4;
    float4v acc[4];
#pragma unroll
    for (int t = 0; t < 4; ++t) acc[t] = (float4v){0.f, 0.f, 0.f, 0.f};

    const ushort_t* abase_s = &sagg[m * SAGG_STR + q * 8];
    const ushort_t* arow_x  = xb + (wrow + m) * IN_DIM + q * 8;
    const ushort_t* bbase   = w1t + (w * 64 + m) * 256 + q * 8;

#pragma unroll
    for (int s = 0; s < 8; ++s) {
        short8 a = (s < 4) ? *(const short8*)(abase_s + s * 32)
                           : *(const short8*)(arow_x + (s - 4) * 32);
#pragma unroll
        for (int t = 0; t < 4; ++t) {
            short8 b = *(const short8*)(bbase + (t * 16) * 256 + s * 32);
            acc[t] = __builtin_amdgcn_mfma_f32_16x16x32_bf16(a, b, acc[t], 0, 0, 0);
        }
    }

#pragma unroll
    for (int t = 0; t < 4; ++t) {
        int col = w * 64 + t * 16 + m;
        float bv = b1[col];
#pragma unroll
        for (int r = 0; r < 4; ++r) {
            int row = wrow + q * 4 + r;
            float v = acc[t][r] + bv;
            v = fmaxf(v, 0.0f);
            hb[row * HID_DIM + col] = f2bf(v);
        }
    }
}

// ---------------------------------------------------------------------------
// MFMA layer 2: which=0 -> Pb = h @ W2_l (bf16); which=1 -> Rf = h @ W2_r (f32)
// ---------------------------------------------------------------------------
__global__ void mfma2_kernel(const ushort_t* __restrict__ hb,
                             const ushort_t* __restrict__ w2tl,
                             const ushort_t* __restrict__ w2tr,
                             ushort_t* __restrict__ Pb,
                             float* __restrict__ Rf) {
    const int wrow = blockIdx.x * 16;
    const int which = blockIdx.y;
    const ushort_t* wt = which ? w2tr : w2tl;
    const int l = threadIdx.x;
    const int m = l & 15, q = l >> 4;

    float4v acc[8];
#pragma unroll
    for (int t = 0; t < 8; ++t) acc[t] = (float4v){0.f, 0.f, 0.f, 0.f};

    const ushort_t* arow  = hb + (wrow + m) * HID_DIM + q * 8;
    const ushort_t* bbase = wt + m * 256 + q * 8;

#pragma unroll
    for (int s = 0; s < 8; ++s) {
        short8 a = *(const short8*)(arow + s * 32);
#pragma unroll
        for (int t = 0; t < 8; ++t) {
            short8 b = *(const short8*)(bbase + (t * 16) * 256 + s * 32);
            acc[t] = __builtin_amdgcn_mfma_f32_16x16x32_bf16(a, b, acc[t], 0, 0, 0);
        }
    }

    if (which == 0) {
#pragma unroll
        for (int t = 0; t < 8; ++t) {
            int col = t * 16 + m;
#pragma unroll
            for (int r = 0; r < 4; ++r)
                Pb[(wrow + q * 4 + r) * OUT_DIM + col] = f2bf(acc[t][r]);
        }
    } else {
#pragma unroll
        for (int t = 0; t < 8; ++t) {
            int col = t * 16 + m;
#pragma unroll
            for (int r = 0; r < 4; ++r)
                Rf[(wrow + q * 4 + r) * OUT_DIM + col] = acc[t][r];
        }
    }
}

// ---------------------------------------------------------------------------
// Final gather + epilogue: out[n][:] = mean_e P[esrc[e]][:] + R[n][:] + b2
// ---------------------------------------------------------------------------
__global__ void gather_final(const ushort_t* __restrict__ Pb,
                             const int* __restrict__ degp,
                             const ushort_t* __restrict__ esrc2,
                             const float* __restrict__ Rf,
                             const float* __restrict__ b2,
                             float* __restrict__ out) {
    const uint4* f = (const uint4*)Pb;            // 16 uint4 per row
    const int n = blockIdx.x;
    const int g = threadIdx.x >> 4;
    const int c = threadIdx.x & 15;
    const int deg = min(degp[n], MAXDEG);
    const ushort_t* idx = esrc2 + n * MAXDEG;

    float a0=0,a1=0,a2=0,a3=0,a4=0,a5=0,a6=0,a7=0;
    for (int e = g; e < deg; e += 4) {
        int s = idx[e];
        uint4 u = f[s * 16 + c];
        a0 += bf_lo(u.x); a1 += bf_hi(u.x);
        a2 += bf_lo(u.y); a3 += bf_hi(u.y);
        a4 += bf_lo(u.z); a5 += bf_hi(u.z);
        a6 += bf_lo(u.w); a7 += bf_hi(u.w);
    }
#pragma unroll
    for (int off = 32; off >= 16; off >>= 1) {
        a0 += __shfl_down(a0, off); a1 += __shfl_down(a1, off);
        a2 += __shfl_down(a2, off); a3 += __shfl_down(a3, off);
        a4 += __shfl_down(a4, off); a5 += __shfl_down(a5, off);
        a6 += __shfl_down(a6, off); a7 += __shfl_down(a7, off);
    }
    if (g == 0) {
        const float dinv = (deg > 0) ? 1.0f / (float)deg : 0.0f;
        const int base = n * OUT_DIM + c * 8;
        float4 r0 = *(const float4*)(Rf + base);
        float4 r1 = *(const float4*)(Rf + base + 4);
        float4 o0, o1;
        o0.x = a0 * dinv + r0.x + b2[c * 8 + 0];
        o0.y = a1 * dinv + r0.y + b2[c * 8 + 1];
        o0.z = a2 * dinv + r0.z + b2[c * 8 + 2];
        o0.w = a3 * dinv + r0.w + b2[c * 8 + 3];
        o1.x = a4 * dinv + r1.x + b2[c * 8 + 4];
        o1.y = a5 * dinv + r1.y + b2[c * 8 + 5];
        o1.z = a6 * dinv + r1.z + b2[c * 8 + 6];
        o1.w = a7 * dinv + r1.w + b2[c * 8 + 7];
        *(float4*)(out + base)     = o0;
        *(float4*)(out + base + 4) = o1;
    }
}

// ---------------------------------------------------------------------------
// Launch
// ---------------------------------------------------------------------------
extern "C" void kernel_launch(void* const* d_in, const int* in_sizes, int n_in,
                              void* d_out, int out_size, void* d_ws, size_t ws_size,
                              hipStream_t stream) {
    const float* x    = (const float*)d_in[0];
    const int*   ei   = (const int*)  d_in[1];
    const float* W1_l = (const float*)d_in[2];
    const float* b1   = (const float*)d_in[3];
    const float* W1_r = (const float*)d_in[4];
    const float* W2_l = (const float*)d_in[5];
    const float* b2   = (const float*)d_in[6];
    const float* W2_r = (const float*)d_in[7];
    float* out = (float*)d_out;

    const int* src = ei;
    const int* dst = ei + N_EDGES;

    // ---- workspace layout (int units) ----
    int* ip = (int*)d_ws;
    int*      HO    = ip;                           // 64*10240 = 655,360 ints
    int*      deg   = ip + 655360;                  // 10,240
    ushort_t* esrc2 = (ushort_t*)(ip + 665600);     // 1,280,000 ushorts
    ushort_t* ub    = (ushort_t*)(ip + 1305600);
    ushort_t* xb   = ub;               // 1,280,000
    ushort_t* Pb   = ub + 1280000;     // 1,280,000
    ushort_t* w1t  = ub + 2560000;     //    65,536
    ushort_t* w2tl = ub + 2625536;     //    32,768
    ushort_t* w2tr = ub + 2658304;     //    32,768
    ushort_t* hb   = ub + 2691072;     // 2,560,000 -> ends 5,251,072
    float*    Rf   = (float*)(ub + 5251072);   // 1,280,000 floats

    // ---- prep + 3-phase counting-sort CSR build ----
    prep_kernel<<<(PREP_TOTAL + 255) / 256, 256, 0, stream>>>(
        x, W1_l, W1_r, W2_l, W2_r, xb, w1t, w2tl, w2tr);
    hist_kernel<<<NCHUNK * NPART, 256, 0, stream>>>(dst, HO);
    scan_kernel<<<40, 256, 0, stream>>>(HO, deg);
    scatter_kernel<<<NCHUNK * NPART, 256, 0, stream>>>(src, dst, HO, esrc2);

    // ---- Layer 1 (fused gather + MFMA) ----
    gather_mfma1_kernel<<<625, 256, 0, stream>>>(xb, deg, esrc2, w1t, b1, hb);

    // ---- Layer 2 (projection trick + fused epilogue) ----
    mfma2_kernel<<<dim3(625, 2), 64, 0, stream>>>(hb, w2tl, w2tr, Pb, Rf);
    gather_final<<<N_NODES, 64, 0, stream>>>(Pb, deg, esrc2, Rf, b2, out);
}

// Round 11
// 164.566 us; speedup vs baseline: 1.1532x; 1.1532x over previous
//
#include <hip/hip_runtime.h>
#include <hip/hip_bf16.h>

#define N_NODES 10000
#define N_EDGES 640000
#define IN_DIM  128
#define HID_DIM 256
#define OUT_DIM 128

#define MAXDEG     128     // deg ~ Binom(640k,1e-4): mean 64, P(>128) ~ 1e-11
#define NCHUNK     64
#define CEDGES     (N_EDGES / NCHUNK)        // 10000 edges per chunk
#define NPART      8
#define PART_NODES (N_NODES / NPART)         // 1250
#define HSTRIDE    10240                     // padded node stride in HO

typedef __attribute__((ext_vector_type(8))) short short8;
typedef __attribute__((ext_vector_type(4))) float float4v;
typedef unsigned short ushort_t;
typedef unsigned int uint_t;

__device__ inline ushort_t f2bf(float f) {
    uint_t u = __float_as_uint(f);
    u += 0x7fffu + ((u >> 16) & 1u);
    return (ushort_t)(u >> 16);
}
__device__ inline float bf_lo(uint_t u) { return __uint_as_float(u << 16); }
__device__ inline float bf_hi(uint_t u) { return __uint_as_float(u & 0xffff0000u); }

// ---------------------------------------------------------------------------
// Fused prep + windowed hist (independent work, one dispatch).
// Blocks [0, PREP_BLOCKS): x -> bf16, weights -> transposed bf16.
// Blocks [PREP_BLOCKS, +NCHUNK*NPART): block (chunk,part) histograms its
// chunk's edges landing in its 1250-node window (5 KB LDS) into HO.
// ---------------------------------------------------------------------------
#define PREP_X   (N_NODES * IN_DIM)
#define PREP_W1  (HID_DIM * (2 * IN_DIM))
#define PREP_W2  (OUT_DIM * HID_DIM)
#define PREP_TOTAL (PREP_X + PREP_W1 + 2 * PREP_W2)
#define PREP_BLOCKS (PREP_TOTAL / 256)       // 5512 exactly

__global__ void prep_hist_kernel(const float* __restrict__ x,
                                 const float* __restrict__ W1_l, const float* __restrict__ W1_r,
                                 const float* __restrict__ W2_l, const float* __restrict__ W2_r,
                                 ushort_t* __restrict__ xb,  ushort_t* __restrict__ w1t,
                                 ushort_t* __restrict__ w2tl, ushort_t* __restrict__ w2tr,
                                 const int* __restrict__ dst, int* __restrict__ HO) {
    __shared__ int h[PART_NODES];
    const int bid = blockIdx.x;
    const int tid = threadIdx.x;
    if (bid < PREP_BLOCKS) {
        int i = bid * 256 + tid;
        if (i < PREP_X) {
            xb[i] = f2bf(x[i]);
        } else if (i < PREP_X + PREP_W1) {
            int j = i - PREP_X;
            int n = j >> 8, k = j & 255;        // w1t[n][k], n in [0,256)
            float v = (k < 128) ? W1_l[k * HID_DIM + n] : W1_r[(k - 128) * HID_DIM + n];
            w1t[j] = f2bf(v);
        } else if (i < PREP_X + PREP_W1 + PREP_W2) {
            int j = i - (PREP_X + PREP_W1);
            int n = j >> 8, k = j & 255;
            w2tl[j] = f2bf(W2_l[k * OUT_DIM + n]);
        } else {
            int j = i - (PREP_X + PREP_W1 + PREP_W2);
            int n = j >> 8, k = j & 255;
            w2tr[j] = f2bf(W2_r[k * OUT_DIM + n]);
        }
        return;
    }
    const int hb_   = bid - PREP_BLOCKS;
    const int part  = hb_ & (NPART - 1);
    const int chunk = hb_ >> 3;
    const int lo    = part * PART_NODES;
    for (int i = tid; i < PART_NODES; i += 256) h[i] = 0;
    __syncthreads();
    const int4* d4 = (const int4*)(dst + chunk * CEDGES);
    for (int i = tid; i < CEDGES / 4; i += 256) {
        int4 v = d4[i];
        int a;
        a = v.x - lo; if ((unsigned)a < (unsigned)PART_NODES) atomicAdd(&h[a], 1);
        a = v.y - lo; if ((unsigned)a < (unsigned)PART_NODES) atomicAdd(&h[a], 1);
        a = v.z - lo; if ((unsigned)a < (unsigned)PART_NODES) atomicAdd(&h[a], 1);
        a = v.w - lo; if ((unsigned)a < (unsigned)PART_NODES) atomicAdd(&h[a], 1);
    }
    __syncthreads();
    int* row = HO + chunk * HSTRIDE + lo;
    for (int i = tid; i < PART_NODES; i += 256) row[i] = h[i];
}

// ---------------------------------------------------------------------------
// CSR phase B: thread n converts column n of HO to exclusive per-chunk
// offsets (coalesced across n) and emits deg[n].
// ---------------------------------------------------------------------------
__global__ void scan_kernel(int* __restrict__ HO, int* __restrict__ deg) {
    int n = blockIdx.x * blockDim.x + threadIdx.x;
    if (n >= N_NODES) return;
    int s = 0;
    for (int b = 0; b < NCHUNK; ++b) {
        int v = HO[b * HSTRIDE + n];
        HO[b * HSTRIDE + n] = s;
        s += v;
    }
    deg[n] = s;
}

// ---------------------------------------------------------------------------
// CSR phase C: scatter with LDS cursors (slots pre-reserved by the scan —
// no global atomics). Block (chunk, part); plain byte-disjoint 2B stores.
// ---------------------------------------------------------------------------
__global__ void scatter_kernel(const int* __restrict__ src, const int* __restrict__ dst,
                               const int* __restrict__ HO, ushort_t* __restrict__ esrc2) {
    __shared__ int cur[PART_NODES];
    const int part  = blockIdx.x & (NPART - 1);
    const int chunk = blockIdx.x >> 3;
    const int lo    = part * PART_NODES;
    const int tid   = threadIdx.x;
    for (int i = tid; i < PART_NODES; i += 256)
        cur[i] = HO[chunk * HSTRIDE + lo + i];
    __syncthreads();
    const int base = chunk * CEDGES;
    for (int e = base + tid; e < base + CEDGES; e += 256) {
        int d = dst[e] - lo;
        if ((unsigned)d < (unsigned)PART_NODES) {
            int pos = atomicAdd(&cur[d], 1);          // LDS atomic, low contention
            if (pos < MAXDEG) esrc2[(lo + d) * MAXDEG + pos] = (ushort_t)src[e];
        }
    }
}

// ---------------------------------------------------------------------------
// Gather-mean over bf16 rows. One 64-thread block per node. 16 lanes x uint4
// cover a 256 B row (stride 16); 4 slot groups x 2-deep unroll -> 8 row
// loads in flight. Shuffle-reduce over slot groups.
// ---------------------------------------------------------------------------
__global__ void gather_mean_bf16(const ushort_t* __restrict__ feat,
                                 const int* __restrict__ degp,
                                 const ushort_t* __restrict__ esrc2,
                                 ushort_t* __restrict__ out) {
    const uint4* f = (const uint4*)feat;          // 16 uint4 per row
    const int n = blockIdx.x;
    const int g = threadIdx.x >> 4;               // slot group 0..3
    const int c = threadIdx.x & 15;               // 16B column 0..15
    const int deg = min(degp[n], MAXDEG);
    const ushort_t* idx = esrc2 + n * MAXDEG;

    float a0=0,a1=0,a2=0,a3=0,a4=0,a5=0,a6=0,a7=0;
    int e = g;
    for (; e + 4 < deg; e += 8) {                 // 2 independent rows in flight
        uint4 u = f[(int)idx[e] * 16 + c];
        uint4 v = f[(int)idx[e + 4] * 16 + c];
        a0 += bf_lo(u.x) + bf_lo(v.x); a1 += bf_hi(u.x) + bf_hi(v.x);
        a2 += bf_lo(u.y) + bf_lo(v.y); a3 += bf_hi(u.y) + bf_hi(v.y);
        a4 += bf_lo(u.z) + bf_lo(v.z); a5 += bf_hi(u.z) + bf_hi(v.z);
        a6 += bf_lo(u.w) + bf_lo(v.w); a7 += bf_hi(u.w) + bf_hi(v.w);
    }
    if (e < deg) {
        uint4 u = f[(int)idx[e] * 16 + c];
        a0 += bf_lo(u.x); a1 += bf_hi(u.x);
        a2 += bf_lo(u.y); a3 += bf_hi(u.y);
        a4 += bf_lo(u.z); a5 += bf_hi(u.z);
        a6 += bf_lo(u.w); a7 += bf_hi(u.w);
    }
#pragma unroll
    for (int off = 32; off >= 16; off >>= 1) {
        a0 += __shfl_down(a0, off); a1 += __shfl_down(a1, off);
        a2 += __shfl_down(a2, off); a3 += __shfl_down(a3, off);
        a4 += __shfl_down(a4, off); a5 += __shfl_down(a5, off);
        a6 += __shfl_down(a6, off); a7 += __shfl_down(a7, off);
    }
    if (g == 0) {
        const float dinv = (deg > 0) ? 1.0f / (float)deg : 0.0f;
        uint4 o;
        o.x = (uint_t)f2bf(a0 * dinv) | ((uint_t)f2bf(a1 * dinv) << 16);
        o.y = (uint_t)f2bf(a2 * dinv) | ((uint_t)f2bf(a3 * dinv) << 16);
        o.z = (uint_t)f2bf(a4 * dinv) | ((uint_t)f2bf(a5 * dinv) << 16);
        o.w = (uint_t)f2bf(a6 * dinv) | ((uint_t)f2bf(a7 * dinv) << 16);
        ((uint4*)out)[n * 16 + c] = o;
    }
}

// ---------------------------------------------------------------------------
// Final gather + epilogue: out[n][:] = mean_e P[esrc[e]][:] + R[n][:] + b2
// ---------------------------------------------------------------------------
__global__ void gather_final(const ushort_t* __restrict__ Pb,
                             const int* __restrict__ degp,
                             const ushort_t* __restrict__ esrc2,
                             const float* __restrict__ Rf,
                             const float* __restrict__ b2,
                             float* __restrict__ out) {
    const uint4* f = (const uint4*)Pb;            // 16 uint4 per row
    const int n = blockIdx.x;
    const int g = threadIdx.x >> 4;
    const int c = threadIdx.x & 15;
    const int deg = min(degp[n], MAXDEG);
    const ushort_t* idx = esrc2 + n * MAXDEG;

    float a0=0,a1=0,a2=0,a3=0,a4=0,a5=0,a6=0,a7=0;
    int e = g;
    for (; e + 4 < deg; e += 8) {
        uint4 u = f[(int)idx[e] * 16 + c];
        uint4 v = f[(int)idx[e + 4] * 16 + c];
        a0 += bf_lo(u.x) + bf_lo(v.x); a1 += bf_hi(u.x) + bf_hi(v.x);
        a2 += bf_lo(u.y) + bf_lo(v.y); a3 += bf_hi(u.y) + bf_hi(v.y);
        a4 += bf_lo(u.z) + bf_lo(v.z); a5 += bf_hi(u.z) + bf_hi(v.z);
        a6 += bf_lo(u.w) + bf_lo(v.w); a7 += bf_hi(u.w) + bf_hi(v.w);
    }
    if (e < deg) {
        uint4 u = f[(int)idx[e] * 16 + c];
        a0 += bf_lo(u.x); a1 += bf_hi(u.x);
        a2 += bf_lo(u.y); a3 += bf_hi(u.y);
        a4 += bf_lo(u.z); a5 += bf_hi(u.z);
        a6 += bf_lo(u.w); a7 += bf_hi(u.w);
    }
#pragma unroll
    for (int off = 32; off >= 16; off >>= 1) {
        a0 += __shfl_down(a0, off); a1 += __shfl_down(a1, off);
        a2 += __shfl_down(a2, off); a3 += __shfl_down(a3, off);
        a4 += __shfl_down(a4, off); a5 += __shfl_down(a5, off);
        a6 += __shfl_down(a6, off); a7 += __shfl_down(a7, off);
    }
    if (g == 0) {
        const float dinv = (deg > 0) ? 1.0f / (float)deg : 0.0f;
        const int base = n * OUT_DIM + c * 8;
        float4 r0 = *(const float4*)(Rf + base);
        float4 r1 = *(const float4*)(Rf + base + 4);
        float4 o0, o1;
        o0.x = a0 * dinv + r0.x + b2[c * 8 + 0];
        o0.y = a1 * dinv + r0.y + b2[c * 8 + 1];
        o0.z = a2 * dinv + r0.z + b2[c * 8 + 2];
        o0.w = a3 * dinv + r0.w + b2[c * 8 + 3];
        o1.x = a4 * dinv + r1.x + b2[c * 8 + 4];
        o1.y = a5 * dinv + r1.y + b2[c * 8 + 5];
        o1.z = a6 * dinv + r1.z + b2[c * 8 + 6];
        o1.w = a7 * dinv + r1.w + b2[c * 8 + 7];
        *(float4*)(out + base)     = o0;
        *(float4*)(out + base + 4) = o1;
    }
}

// ---------------------------------------------------------------------------
// MFMA layer 1: h = relu([agg|x] @ [W1_l;W1_r] + b1), bf16 out. K=256.
// A-frag: A[m=lane&15][k=q*8+j]; B-frag: Wt[n=lane&15][k=q*8+j];
// C/D: col=lane&15, row=q*4+reg (m89-verified layouts).
// ---------------------------------------------------------------------------
__global__ void mfma1_kernel(const ushort_t* __restrict__ aggb,
                             const ushort_t* __restrict__ xb,
                             const ushort_t* __restrict__ w1t,
                             const float* __restrict__ b1,
                             ushort_t* __restrict__ hb) {
    const int wrow = blockIdx.x * 16;
    const int half = blockIdx.y;
    const int l = threadIdx.x;
    const int m = l & 15, q = l >> 4;

    float4v acc[8];
#pragma unroll
    for (int t = 0; t < 8; ++t) acc[t] = (float4v){0.f, 0.f, 0.f, 0.f};

    const ushort_t* arow_a = aggb + (wrow + m) * IN_DIM + q * 8;
    const ushort_t* arow_x = xb   + (wrow + m) * IN_DIM + q * 8;
    const ushort_t* bbase  = w1t + (half * 128 + m) * 256 + q * 8;

#pragma unroll
    for (int s = 0; s < 8; ++s) {
        const ushort_t* ap = (s < 4) ? (arow_a + s * 32) : (arow_x + (s - 4) * 32);
        short8 a = *(const short8*)ap;
#pragma unroll
        for (int t = 0; t < 8; ++t) {
            short8 b = *(const short8*)(bbase + (t * 16) * 256 + s * 32);
            acc[t] = __builtin_amdgcn_mfma_f32_16x16x32_bf16(a, b, acc[t], 0, 0, 0);
        }
    }

#pragma unroll
    for (int t = 0; t < 8; ++t) {
        int col = half * 128 + t * 16 + m;
        float bv = b1[col];
#pragma unroll
        for (int r = 0; r < 4; ++r) {
            int row = wrow + q * 4 + r;
            float v = acc[t][r] + bv;
            v = fmaxf(v, 0.0f);
            hb[row * HID_DIM + col] = f2bf(v);
        }
    }
}

// ---------------------------------------------------------------------------
// MFMA layer 2: which=0 -> Pb = h @ W2_l (bf16); which=1 -> Rf = h @ W2_r (f32)
// ---------------------------------------------------------------------------
__global__ void mfma2_kernel(const ushort_t* __restrict__ hb,
                             const ushort_t* __restrict__ w2tl,
                             const ushort_t* __restrict__ w2tr,
                             ushort_t* __restrict__ Pb,
                             float* __restrict__ Rf) {
    const int wrow = blockIdx.x * 16;
    const int which = blockIdx.y;
    const ushort_t* wt = which ? w2tr : w2tl;
    const int l = threadIdx.x;
    const int m = l & 15, q = l >> 4;

    float4v acc[8];
#pragma unroll
    for (int t = 0; t < 8; ++t) acc[t] = (float4v){0.f, 0.f, 0.f, 0.f};

    const ushort_t* arow  = hb + (wrow + m) * HID_DIM + q * 8;
    const ushort_t* bbase = wt + m * 256 + q * 8;

#pragma unroll
    for (int s = 0; s < 8; ++s) {
        short8 a = *(const short8*)(arow + s * 32);
#pragma unroll
        for (int t = 0; t < 8; ++t) {
            short8 b = *(const short8*)(bbase + (t * 16) * 256 + s * 32);
            acc[t] = __builtin_amdgcn_mfma_f32_16x16x32_bf16(a, b, acc[t], 0, 0, 0);
        }
    }

    if (which == 0) {
#pragma unroll
        for (int t = 0; t < 8; ++t) {
            int col = t * 16 + m;
#pragma unroll
            for (int r = 0; r < 4; ++r)
                Pb[(wrow + q * 4 + r) * OUT_DIM + col] = f2bf(acc[t][r]);
        }
    } else {
#pragma unroll
        for (int t = 0; t < 8; ++t) {
            int col = t * 16 + m;
#pragma unroll
            for (int r = 0; r < 4; ++r)
                Rf[(wrow + q * 4 + r) * OUT_DIM + col] = acc[t][r];
        }
    }
}

// ---------------------------------------------------------------------------
// Launch
// ---------------------------------------------------------------------------
extern "C" void kernel_launch(void* const* d_in, const int* in_sizes, int n_in,
                              void* d_out, int out_size, void* d_ws, size_t ws_size,
                              hipStream_t stream) {
    const float* x    = (const float*)d_in[0];
    const int*   ei   = (const int*)  d_in[1];
    const float* W1_l = (const float*)d_in[2];
    const float* b1   = (const float*)d_in[3];
    const float* W1_r = (const float*)d_in[4];
    const float* W2_l = (const float*)d_in[5];
    const float* b2   = (const float*)d_in[6];
    const float* W2_r = (const float*)d_in[7];
    float* out = (float*)d_out;

    const int* src = ei;
    const int* dst = ei + N_EDGES;

    // ---- workspace layout (int units) ----
    int* ip = (int*)d_ws;
    int*      HO    = ip;                           // 64*10240 = 655,360 ints
    int*      deg   = ip + 655360;                  // 10,240
    ushort_t* esrc2 = (ushort_t*)(ip + 665600);     // 1,280,000 ushorts
    ushort_t* ub    = (ushort_t*)(ip + 1305600);
    ushort_t* xb   = ub;               // 1,280,000
    ushort_t* aggb = ub + 1280000;     // 1,280,000 (reused as Pb after mfma1)
    ushort_t* w1t  = ub + 2560000;     //    65,536
    ushort_t* w2tl = ub + 2625536;     //    32,768
    ushort_t* w2tr = ub + 2658304;     //    32,768
    ushort_t* hb   = ub + 2691072;     // 2,560,000 -> ends 5,251,072
    ushort_t* Pb   = aggb;             // alias: aggb dead after mfma1
    float*    Rf   = (float*)(ub + 5251072);   // 1,280,000 floats

    // ---- fused prep + hist, then scan + scatter ----
    prep_hist_kernel<<<PREP_BLOCKS + NCHUNK * NPART, 256, 0, stream>>>(
        x, W1_l, W1_r, W2_l, W2_r, xb, w1t, w2tl, w2tr, dst, HO);
    scan_kernel<<<40, 256, 0, stream>>>(HO, deg);
    scatter_kernel<<<NCHUNK * NPART, 256, 0, stream>>>(src, dst, HO, esrc2);

    // ---- Layer 1 ----
    gather_mean_bf16<<<N_NODES, 64, 0, stream>>>(xb, deg, esrc2, aggb);
    mfma1_kernel<<<dim3(625, 2), 64, 0, stream>>>(aggb, xb, w1t, b1, hb);

    // ---- Layer 2 (projection trick + fused epilogue) ----
    mfma2_kernel<<<dim3(625, 2), 64, 0, stream>>>(hb, w2tl, w2tr, Pb, Rf);
    gather_final<<<N_NODES, 64, 0, stream>>>(Pb, deg, esrc2, Rf, b2, out);
}